// Round 22
// baseline (160.057 us; speedup 1.0000x reference)
//
#include <hip/hip_runtime.h>
#include <hip/hip_fp16.h>
#include <math.h>

// StressCapsuleLayer: capsule dynamic routing (3 iters), fused recompute design.
//   x [128][648][16] f32, W [648][32][32][16] f32 -> v [128][32][32] f32
//
//   pass0: c = 1/32 -> s0 -> v0 = squash(s0)            [f16 MFMA GEMM]
//   pass1: logit = <u_hat, v0>          -> softmax_j -> s1 -> v1
//   pass2: logit = <u, v0+v1> (linear)  -> softmax_j -> s2 -> v2 = output
//
// R22: barrier elimination in the phases. After the logit shfl, each lane
// holds logit(j_q, b=lane) IN REGISTERS. The only cross-wave quantity the
// softmax needs is Z(b) = sum_j exp(logit). So: per-lane exp + LDS atomicAdd
// into Z[b] (32 slots, conflict-free) -> ONE barrier -> c = e/Z from regs.
// Removes 1 of 3 barriers, the softmax phase, all lg traffic, and max-sub
// (safe: |logit| <= |u|2*|v|2 <= ~12, exp <= e^12). Z dbuf 256B, zeroed in
// post-B slack. s-accum stays in-regs (R21). pass0 reverted to R18/R20
// 512-thr 2n form (R21's 1024-thr pass0 was the likely 4% regression).
// Spill detectors: VGPR<=128, phase WRITE ~17MB/pass.

#define N_IN 648
#define ELEMS 131072      // 128*32*32 output elements

// d_ws layout (bytes): v0 @0 (512KB), vsum @524288, wf16 @1048576 (21233664),
// parts(f16) @22282240 (NC x 262144)
#define WF16_OFF 1048576
#define PARTS_OFF 22282240

// pass0 LDS arena (R18): WF[2] @0/65536 (2n x 32KB), X[2] @131072/135168.
// Epilogue reuse [32][1036] f32 = 132608 <= 147456.
#define P0X_OFF 131072
#define ARENA_P0 147456

// phase LDS arena: WF[2] @0/32768, X[2] @65536/67584 (2KB each),
// Z[2] @69632 (2 x 128B). Epilogue reuse [16][1036] f32 = 66304 <= 69888.
#define XF_OFF 65536
#define ZOFF 69632
#define ARENA_PH 69888

typedef __attribute__((ext_vector_type(8))) _Float16 f16x8;
typedef __attribute__((ext_vector_type(16))) float f32x16;

union F16U { uint4 u; f16x8 f; };
union HU { __half h; unsigned short us; };

__device__ __forceinline__ unsigned pkh(float a, float b) {
  HU x, y; x.h = __float2half(a); y.h = __float2half(b);
  return (unsigned)x.us | ((unsigned)y.us << 16);
}
__device__ __forceinline__ float h2f(unsigned short u) {
  HU x; x.us = u; return __half2float(x.h);
}

// cvt one W row (16 f32 in r[0..3]) to f16, write its two frag slots:
// (d,h=0) = i0..7 at jS*1024 + d*16; (d,h=1) = i8..15 at +512.
__device__ __forceinline__ void writeW(char* wbuf, int jS, int d, const float4* r) {
  uint4 h0, h1;
  h0.x = pkh(r[0].x, r[0].y); h0.y = pkh(r[0].z, r[0].w);
  h0.z = pkh(r[1].x, r[1].y); h0.w = pkh(r[1].z, r[1].w);
  h1.x = pkh(r[2].x, r[2].y); h1.y = pkh(r[2].z, r[2].w);
  h1.z = pkh(r[3].x, r[3].y); h1.w = pkh(r[3].z, r[3].w);
  *(uint4*)(wbuf + jS * 1024 + d * 16) = h0;
  *(uint4*)(wbuf + jS * 1024 + 512 + d * 16) = h1;
}
__device__ __forceinline__ void loadW(float4* r, const float* __restrict__ W,
                                      int n, int jS, int d) {
  const float4* rp = (const float4*)(W + (size_t)n * 16384 + jS * 512 + d * 16);
  r[0] = rp[0]; r[1] = rp[1]; r[2] = rp[2]; r[3] = rp[3];
}

// one-time: W f32 -> f16 frag-layout blocks in d_ws (32KB per n)
__global__ __launch_bounds__(512) void cvt_w_f16(const float* __restrict__ W,
                                                 char* __restrict__ wf) {
  const int n = blockIdx.x;
  const int t = threadIdx.x;
  const int jS = t >> 4, m = t & 15;
  float4 rA[4], rB[4];
  loadW(rA, W, n, jS, m);
  loadW(rB, W, n, jS, m + 16);
  char* dst = wf + (size_t)n * 32768;
  writeW(dst, jS, m, rA);
  writeW(dst, jS, m + 16, rB);
}

// stage cnt (1 or 2) consecutive n's of Wf16 + x rows (512-thread version)
__device__ __forceinline__ void stage_pair(char* nwf, char* nxb,
                                           const char* __restrict__ wf16,
                                           const float* __restrict__ x,
                                           int nbase, int cnt, int b0, int t) {
  const char* src = wf16 + (size_t)nbase * 32768;
  for (int r = 0; r < cnt * 4; ++r)
    *(uint4*)(nwf + r * 8192 + t * 16) = *(const uint4*)(src + r * 8192 + t * 16);
  if (t < 128) {
    const int s2 = t >> 6, u = t & 63;
    if (s2 < cnt) {
      const float4* xp = (const float4*)(
          x + ((size_t)(b0 + (u & 31)) * N_IN + nbase + s2) * 16 + (u >> 5) * 8);
      *(float4*)(nxb + s2 * 2048 + u * 16) = xp[0];
      *(float4*)(nxb + s2 * 2048 + 1024 + u * 16) = xp[1];
    }
  }
}

// 512-thr epilogue (pass0): scatter acc ([32][1036] reuse), f16 parts.
__device__ __forceinline__ void store_parts(char* arena, __half* __restrict__ parts,
                                            const f32x16* acc, float scale,
                                            int nchunk, int b0, int t) {
  const int w = t >> 6, l = t & 63;
  const int b32 = l & 31, half = l >> 5;
  __syncthreads();
#pragma unroll
  for (int q = 0; q < 4; ++q) {
    const int j = w * 4 + q;
#pragma unroll
    for (int g = 0; g < 4; ++g) {
      float4 v4;
      v4.x = acc[q][g * 4 + 0] * scale;
      v4.y = acc[q][g * 4 + 1] * scale;
      v4.z = acc[q][g * 4 + 2] * scale;
      v4.w = acc[q][g * 4 + 3] * scale;
      *(float4*)(arena + (b32 * 1036 + j * 32 + g * 8 + 4 * half) * 4) = v4;
    }
  }
  __syncthreads();
  char* pb = (char*)(parts + (size_t)nchunk * ELEMS + (size_t)b0 * 1024);
  const int rb = t >> 4, c16 = t & 15;
#pragma unroll
  for (int q = 0; q < 8; ++q) {
    const int g8 = c16 + q * 16;
    const float4 a = *(const float4*)(arena + (rb * 1036 + g8 * 8) * 4);
    const float4 b = *(const float4*)(arena + (rb * 1036 + g8 * 8 + 4) * 4);
    *(uint4*)(pb + rb * 2048 + g8 * 16) =
        uint4{pkh(a.x, a.y), pkh(a.z, a.w), pkh(b.x, b.y), pkh(b.z, b.w)};
  }
}

// XCD-aware decode: 4 btile-sharers of an n-chunk -> same XCD
__device__ __forceinline__ void decode_bid(int bid, int NC, int& nchunk, int& btile) {
  if ((NC & 7) == 0) {
    const int r = bid & 7;
    btile = (bid >> 3) & 3;
    nchunk = (bid >> 5) * 8 + r;
  } else {
    nchunk = bid >> 2;
    btile = bid & 3;
  }
}

// ---------------- pass 0 (R18/R20-validated): 2n per buffer, 512 thr --------
__global__ __launch_bounds__(512, 1) void caps_pass0_mfma(
    const float* __restrict__ x, const char* __restrict__ wf16,
    __half* __restrict__ parts, int NC)
{
  __shared__ __align__(16) char arena[ARENA_P0];
  const int t = threadIdx.x;
  const int w = t >> 6, l = t & 63;
  int nchunk, btile;
  decode_bid(blockIdx.x, NC, nchunk, btile);
  const int n0 = (N_IN * nchunk) / NC;
  const int n1 = (N_IN * (nchunk + 1)) / NC;
  const int b0 = btile * 32;

  f32x16 acc[4];
#pragma unroll
  for (int q = 0; q < 4; ++q) acc[q] = (f32x16)(0.0f);

  stage_pair(arena, arena + P0X_OFF, wf16, x, n0, (n1 - n0 >= 2) ? 2 : 1, b0, t);

  int cur = 0;
  for (int base = n0; base < n1; base += 2) {
    const int cnt = (n1 - base >= 2) ? 2 : 1;
    __syncthreads();
    const char* wf = arena + cur * 65536;
    const char* xb = arena + P0X_OFF + cur * 4096;

    for (int s = 0; s < cnt; ++s) {
      const float4 xw0 = *(const float4*)(xb + s * 2048 + l * 16);
      const float4 xw1 = *(const float4*)(xb + s * 2048 + 1024 + l * 16);
      F16U bf;
      bf.u = uint4{pkh(xw0.x, xw0.y), pkh(xw0.z, xw0.w),
                   pkh(xw1.x, xw1.y), pkh(xw1.z, xw1.w)};
#pragma unroll
      for (int q = 0; q < 4; ++q) {
        const int j = w * 4 + q;
        const f16x8 af = *(const f16x8*)(wf + s * 32768 + j * 1024 + l * 16);
        acc[q] = __builtin_amdgcn_mfma_f32_32x32x16_f16(af, bf.f, acc[q], 0, 0, 0);
      }
    }

    if (base + 2 < n1) {
      const int ncnt = (n1 - (base + 2) >= 2) ? 2 : 1;
      stage_pair(arena + (cur ^ 1) * 65536, arena + P0X_OFF + (cur ^ 1) * 4096,
                 wf16, x, base + 2, ncnt, b0, t);
    }
    cur ^= 1;
  }
  store_parts(arena, parts, acc, 0.03125f, nchunk, b0, t);
}

// ------------- phases 1/2: 1024 thr, 2 barriers/n, Z-atomic softmax ---------
__global__ __launch_bounds__(1024, 1) void caps_phase_mfma(
    const float* __restrict__ x, const char* __restrict__ wf16,
    const float* __restrict__ v,      // v0 (phase1) or v0+v1 (phase2)
    __half* __restrict__ parts, int NC)
{
  __shared__ __align__(16) char arena[ARENA_PH];
  const int t = threadIdx.x;
  const int w = t >> 6, l = t & 63;     // w 0..15, 2 j per wave
  const int b32 = l & 31, half = l >> 5;
  int nchunk, btile;
  decode_bid(blockIdx.x, NC, nchunk, btile);
  const int n0 = (N_IN * nchunk) / NC;
  const int n1 = (N_IN * (nchunk + 1)) / NC;
  const int b0 = btile * 32;

  // v gather ONCE into 16 packed-f16 regs: vw[q][p] covers k=2p,2p+1;
  // d(k) = (k&3)+8*(k>>2)+4*half (ut C-reg order). [R14-validated]
  unsigned vw[2][8];
  {
    const int bv = b0 + b32;
#pragma unroll
    for (int q = 0; q < 2; ++q) {
      const int j = w * 2 + q;
#pragma unroll
      for (int g = 0; g < 4; ++g) {
        const float4 g4 = *(const float4*)(v + (size_t)bv * 1024 + j * 32 + g * 8 + 4 * half);
        vw[q][2 * g]     = pkh(g4.x, g4.y);
        vw[q][2 * g + 1] = pkh(g4.z, g4.w);
      }
    }
  }

  // prologue: stage tile n0 into buffer 0; zero both Z buffers
  {
    const char* src = wf16 + (size_t)n0 * 32768;
    *(uint4*)(arena + t * 16) = *(const uint4*)(src + t * 16);
    *(uint4*)(arena + 16384 + t * 16) = *(const uint4*)(src + 16384 + t * 16);
    if (t < 64) {
      const float4* xp = (const float4*)(x + ((size_t)(b0 + (t & 31)) * N_IN + n0) * 16 + (t >> 5) * 8);
      *(float4*)(arena + XF_OFF + t * 16) = xp[0];
      *(float4*)(arena + XF_OFF + 1024 + t * 16) = xp[1];
      *(float*)(arena + ZOFF + t * 4) = 0.f;   // Z[0][32] + Z[1][32]
    }
  }

  f32x16 acc[2];
  acc[0] = (f32x16)(0.0f);
  acc[1] = (f32x16)(0.0f);

  int cur = 0;
  for (int n = n0; n < n1; ++n) {
    __syncthreads();                    // A: buf[cur] + Z[cur] (zeroed) ready
    const char* wf = arena + cur * 32768;
    const char* xb = arena + XF_OFF + cur * 2048;
    char* nwf = arena + (cur ^ 1) * 32768;
    char* nxb = arena + XF_OFF + (cur ^ 1) * 2048;
    const bool more = (n + 1 < n1);

    // T14: issue next-tile loads now; ds_writes after barrier B
    uint4 tw0, tw1;
    float4 xt0, xt1;
    if (more) {
      const char* src = wf16 + (size_t)(n + 1) * 32768;
      tw0 = *(const uint4*)(src + t * 16);
      tw1 = *(const uint4*)(src + 16384 + t * 16);
      if (t < 64) {
        const float4* xp = (const float4*)(x + ((size_t)(b0 + (t & 31)) * N_IN + n + 1) * 16 + (t >> 5) * 8);
        xt0 = xp[0]; xt1 = xp[1];
      }
    }

    const float4 xw0 = *(const float4*)(xb + l * 16);
    const float4 xw1 = *(const float4*)(xb + 1024 + l * 16);
    F16U bf;
    bf.u = uint4{pkh(xw0.x, xw0.y), pkh(xw0.z, xw0.w),
                 pkh(xw1.x, xw1.y), pkh(xw1.z, xw1.w)};

    // ---- logit pass: u2 + e2 kept in regs; Z accumulated via LDS atomics ----
    f32x16 u2[2];
    float e2[2];
#pragma unroll
    for (int q = 0; q < 2; ++q) {
      const int j = w * 2 + q;
      const f16x8 af = *(const f16x8*)(wf + j * 1024 + l * 16);
      f32x16 ut = (f32x16)(0.0f);
      ut = __builtin_amdgcn_mfma_f32_32x32x16_f16(af, bf.f, ut, 0, 0, 0);
      u2[q] = ut;
      float a = 0.f;
#pragma unroll
      for (int k = 0; k < 16; ++k) {
        const unsigned short us = (k & 1) ? (unsigned short)(vw[q][k >> 1] >> 16)
                                          : (unsigned short)(vw[q][k >> 1] & 0xFFFF);
        a = fmaf(ut[k], h2f(us), a);
      }
      a += __shfl_xor(a, 32);           // full logit(j_q, b32) in-register
      e2[q] = __expf(a);                // no max-sub: |logit| <= ~12, safe
    }
    if (half == 0) {                    // one contributor per (j,b): 32 lanes
      float* Zp = (float*)(arena + ZOFF + cur * 128 + b32 * 4);
      atomicAdd(Zp, e2[0]);
      atomicAdd(Zp, e2[1]);
    }
    __syncthreads();                    // B: Z complete; buf[cur] reads done

    // write prefetched tile; zero Z[cur^1] for next iter
    if (more) {
      *(uint4*)(nwf + t * 16) = tw0;
      *(uint4*)(nwf + 16384 + t * 16) = tw1;
      if (t < 64) {
        *(float4*)(nxb + t * 16) = xt0;
        *(float4*)(nxb + 1024 + t * 16) = xt1;
      }
    }
    if (t < 32) *(float*)(arena + ZOFF + (cur ^ 1) * 128 + t * 4) = 0.f;

    // ---- s accumulate: c = e2/Z(b32) from regs + one broadcast LDS read ----
    const float Zb = *(const float*)(arena + ZOFF + cur * 128 + b32 * 4);
    const float rZ = __frcp_rn(Zb);
#pragma unroll
    for (int q = 0; q < 2; ++q) {
      const float cq = e2[q] * rZ;
#pragma unroll
      for (int k = 0; k < 16; ++k)
        acc[q][k] = fmaf(cq, u2[q][k], acc[q][k]);
    }
    cur ^= 1;
  }

  // epilogue (2 rounds over b-halves, [16][1036] f32 reuse)
#pragma unroll
  for (int r = 0; r < 2; ++r) {
    __syncthreads();
    if ((b32 >> 4) == r) {
      const int b16 = b32 & 15;
#pragma unroll
      for (int q = 0; q < 2; ++q) {
        const int j = w * 2 + q;
#pragma unroll
        for (int g = 0; g < 4; ++g) {
          float4 v4;
          v4.x = acc[q][g * 4 + 0];
          v4.y = acc[q][g * 4 + 1];
          v4.z = acc[q][g * 4 + 2];
          v4.w = acc[q][g * 4 + 3];
          *(float4*)(arena + (b16 * 1036 + j * 32 + g * 8 + 4 * half) * 4) = v4;
        }
      }
    }
    __syncthreads();
    char* pb = (char*)(parts + (size_t)nchunk * ELEMS + (size_t)(b0 + r * 16) * 1024);
    const int rb = t >> 6, c64 = t & 63;   // 16 rows x 64 threads
#pragma unroll
    for (int q2 = 0; q2 < 2; ++q2) {
      const int g8 = c64 + q2 * 64;        // 8-f32 group 0..127
      const float4 a = *(const float4*)(arena + (rb * 1036 + g8 * 8) * 4);
      const float4 b = *(const float4*)(arena + (rb * 1036 + g8 * 8 + 4) * 4);
      *(uint4*)(pb + rb * 2048 + g8 * 16) =
          uint4{pkh(a.x, a.y), pkh(a.z, a.w), pkh(b.x, b.y), pkh(b.z, b.w)};
    }
  }
}

// stage B: sum NC f16 partials (4 elems/thread via uint2), squash over rows
// of 32 (= 8 threads: in-thread 4 + shfl over offs 4,2,1); add prev v if set.
__global__ void reduce_squash4(const unsigned short* __restrict__ parts, int NC,
                               float* __restrict__ out,
                               const float* __restrict__ addprev) {
  const int e0 = (blockIdx.x * 256 + threadIdx.x) * 4;
  float s0 = 0.f, s1 = 0.f, s2v = 0.f, s3 = 0.f;
  for (int c = 0; c < NC; ++c) {
    const uint2 p = *(const uint2*)(parts + (size_t)c * ELEMS + e0);
    s0 += h2f((unsigned short)(p.x & 0xFFFF));
    s1 += h2f((unsigned short)(p.x >> 16));
    s2v += h2f((unsigned short)(p.y & 0xFFFF));
    s3 += h2f((unsigned short)(p.y >> 16));
  }
  float s2 = s0 * s0 + s1 * s1 + s2v * s2v + s3 * s3;
#pragma unroll
  for (int off = 4; off >= 1; off >>= 1) s2 += __shfl_xor(s2, off);
  const float scale = (s2 / (1.0f + s2)) * rsqrtf(s2 + 1e-7f);
  float4 o;
  o.x = s0 * scale; o.y = s1 * scale; o.z = s2v * scale; o.w = s3 * scale;
  if (addprev) {
    const float4 ap = *(const float4*)(addprev + e0);
    o.x += ap.x; o.y += ap.y; o.z += ap.z; o.w += ap.w;
  }
  *(float4*)(out + e0) = o;
}

extern "C" void kernel_launch(void* const* d_in, const int* in_sizes, int n_in,
                              void* d_out, int out_size, void* d_ws, size_t ws_size,
                              hipStream_t stream) {
  const float* x = (const float*)d_in[0];
  const float* W = (const float*)d_in[1];
  float* out = (float*)d_out;

  float* v0 = (float*)d_ws;
  float* vsum = v0 + ELEMS;
  char* wf16 = (char*)d_ws + WF16_OFF;
  __half* parts = (__half*)((char*)d_ws + PARTS_OFF);

  // NC from remaining workspace (deterministic); NC=64 -> grid 256 = 1/CU
  size_t rem = ws_size > (size_t)PARTS_OFF ? ws_size - PARTS_OFF : 0;
  int NC = (int)(rem / (ELEMS * 2));
  NC = NC < 1 ? 1 : (NC > 64 ? 64 : NC);

  const dim3 blk512(512);
  const dim3 blk1k(1024);
  const dim3 gridP(NC * 4);
  const dim3 gridR(128);
  const dim3 blkR(256);

  cvt_w_f16<<<dim3(N_IN), blk512, 0, stream>>>(W, wf16);

  caps_pass0_mfma<<<gridP, blk512, 0, stream>>>(x, wf16, parts, NC);
  reduce_squash4<<<gridR, blkR, 0, stream>>>((const unsigned short*)parts, NC, v0, nullptr);

  caps_phase_mfma<<<gridP, blk1k, 0, stream>>>(x, wf16, v0, parts, NC);
  reduce_squash4<<<gridR, blkR, 0, stream>>>((const unsigned short*)parts, NC, vsum, v0);

  caps_phase_mfma<<<gridP, blk1k, 0, stream>>>(x, wf16, vsum, parts, NC);
  reduce_squash4<<<gridR, blkR, 0, stream>>>((const unsigned short*)parts, NC, out, nullptr);
}

// Round 23
// 146.674 us; speedup vs baseline: 1.0912x; 1.0912x over previous
//
#include <hip/hip_runtime.h>
#include <hip/hip_fp16.h>
#include <math.h>

// StressCapsuleLayer: capsule dynamic routing (3 iters), fused recompute design.
//   x [128][648][16] f32, W [648][32][32][16] f32 -> v [128][32][32] f32
//
//   pass0: c = 1/32 -> s0 -> v0 = squash(s0)            [f16 MFMA GEMM]
//   pass1: logit = <u_hat, v0>          -> softmax_j -> s1 -> v1
//   pass2: logit = <u, v0+v1> (linear)  -> softmax_j -> s2 -> v2 = output
//
// R23: revert to R20 (141.5us, best known). R21/R22 post-mortem: 1024-thr
// kernels get a 64-VGPR compiler cap (R22 counter: VGPR=64, Occ 35%) -> any
// structure keeping MFMA outputs (u2, 32 regs) live across barriers spills
// (R22 WRITE 24.8MB, MfmaUtil 2.2). R20's phase (s-pass re-reads af, nothing
// big live across barriers) fits the cap. Only change vs R20: vectorized
// reduce_squash4 (4 f16/thread via uint2, 8-lane shfl) -- orthogonal,
// register-safe, ~3x4us saved.
// Spill detectors: phase WRITE ~17MB/pass.

#define N_IN 648
#define ELEMS 131072      // 128*32*32 output elements

// d_ws layout (bytes): v0 @0 (512KB), vsum @524288, wf16 @1048576 (21233664),
// parts(f16) @22282240 (NC x 262144)
#define WF16_OFF 1048576
#define PARTS_OFF 22282240

// pass0 LDS arena (R18): WF[2] @0/65536 (2n x 32KB), X[2] @131072/135168.
// Epilogue reuse [32][1036] f32 = 132608 <= 147456.
#define P0X_OFF 131072
#define ARENA_P0 147456

// phase LDS arena: WF[2] @0/32768, X[2] @65536/67584 (2KB each), LG @69632
// (4KB). Epilogue reuse [16][1036] f32 = 66304 <= 73728.
#define XF_OFF 65536
#define LG 69632
#define ARENA_PH 73728

typedef __attribute__((ext_vector_type(8))) _Float16 f16x8;
typedef __attribute__((ext_vector_type(16))) float f32x16;

union F16U { uint4 u; f16x8 f; };
union HU { __half h; unsigned short us; };

__device__ __forceinline__ unsigned pkh(float a, float b) {
  HU x, y; x.h = __float2half(a); y.h = __float2half(b);
  return (unsigned)x.us | ((unsigned)y.us << 16);
}
__device__ __forceinline__ float h2f(unsigned short u) {
  HU x; x.us = u; return __half2float(x.h);
}

// cvt one W row (16 f32 in r[0..3]) to f16, write its two frag slots:
// (d,h=0) = i0..7 at jS*1024 + d*16; (d,h=1) = i8..15 at +512.
__device__ __forceinline__ void writeW(char* wbuf, int jS, int d, const float4* r) {
  uint4 h0, h1;
  h0.x = pkh(r[0].x, r[0].y); h0.y = pkh(r[0].z, r[0].w);
  h0.z = pkh(r[1].x, r[1].y); h0.w = pkh(r[1].z, r[1].w);
  h1.x = pkh(r[2].x, r[2].y); h1.y = pkh(r[2].z, r[2].w);
  h1.z = pkh(r[3].x, r[3].y); h1.w = pkh(r[3].z, r[3].w);
  *(uint4*)(wbuf + jS * 1024 + d * 16) = h0;
  *(uint4*)(wbuf + jS * 1024 + 512 + d * 16) = h1;
}
__device__ __forceinline__ void loadW(float4* r, const float* __restrict__ W,
                                      int n, int jS, int d) {
  const float4* rp = (const float4*)(W + (size_t)n * 16384 + jS * 512 + d * 16);
  r[0] = rp[0]; r[1] = rp[1]; r[2] = rp[2]; r[3] = rp[3];
}

// one-time: W f32 -> f16 frag-layout blocks in d_ws (32KB per n)
__global__ __launch_bounds__(512) void cvt_w_f16(const float* __restrict__ W,
                                                 char* __restrict__ wf) {
  const int n = blockIdx.x;
  const int t = threadIdx.x;
  const int jS = t >> 4, m = t & 15;
  float4 rA[4], rB[4];
  loadW(rA, W, n, jS, m);
  loadW(rB, W, n, jS, m + 16);
  char* dst = wf + (size_t)n * 32768;
  writeW(dst, jS, m, rA);
  writeW(dst, jS, m + 16, rB);
}

// stage cnt (1 or 2) consecutive n's of Wf16 + x rows (512-thread version)
__device__ __forceinline__ void stage_pair(char* nwf, char* nxb,
                                           const char* __restrict__ wf16,
                                           const float* __restrict__ x,
                                           int nbase, int cnt, int b0, int t) {
  const char* src = wf16 + (size_t)nbase * 32768;
  for (int r = 0; r < cnt * 4; ++r)
    *(uint4*)(nwf + r * 8192 + t * 16) = *(const uint4*)(src + r * 8192 + t * 16);
  if (t < 128) {
    const int s2 = t >> 6, u = t & 63;
    if (s2 < cnt) {
      const float4* xp = (const float4*)(
          x + ((size_t)(b0 + (u & 31)) * N_IN + nbase + s2) * 16 + (u >> 5) * 8);
      *(float4*)(nxb + s2 * 2048 + u * 16) = xp[0];
      *(float4*)(nxb + s2 * 2048 + 1024 + u * 16) = xp[1];
    }
  }
}

// 512-thr epilogue (pass0): scatter acc ([32][1036] reuse), f16 parts.
__device__ __forceinline__ void store_parts(char* arena, __half* __restrict__ parts,
                                            const f32x16* acc, float scale,
                                            int nchunk, int b0, int t) {
  const int w = t >> 6, l = t & 63;
  const int b32 = l & 31, half = l >> 5;
  __syncthreads();
#pragma unroll
  for (int q = 0; q < 4; ++q) {
    const int j = w * 4 + q;
#pragma unroll
    for (int g = 0; g < 4; ++g) {
      float4 v4;
      v4.x = acc[q][g * 4 + 0] * scale;
      v4.y = acc[q][g * 4 + 1] * scale;
      v4.z = acc[q][g * 4 + 2] * scale;
      v4.w = acc[q][g * 4 + 3] * scale;
      *(float4*)(arena + (b32 * 1036 + j * 32 + g * 8 + 4 * half) * 4) = v4;
    }
  }
  __syncthreads();
  char* pb = (char*)(parts + (size_t)nchunk * ELEMS + (size_t)b0 * 1024);
  const int rb = t >> 4, c16 = t & 15;
#pragma unroll
  for (int q = 0; q < 8; ++q) {
    const int g8 = c16 + q * 16;
    const float4 a = *(const float4*)(arena + (rb * 1036 + g8 * 8) * 4);
    const float4 b = *(const float4*)(arena + (rb * 1036 + g8 * 8 + 4) * 4);
    *(uint4*)(pb + rb * 2048 + g8 * 16) =
        uint4{pkh(a.x, a.y), pkh(a.z, a.w), pkh(b.x, b.y), pkh(b.z, b.w)};
  }
}

// XCD-aware decode: 4 btile-sharers of an n-chunk -> same XCD
__device__ __forceinline__ void decode_bid(int bid, int NC, int& nchunk, int& btile) {
  if ((NC & 7) == 0) {
    const int r = bid & 7;
    btile = (bid >> 3) & 3;
    nchunk = (bid >> 5) * 8 + r;
  } else {
    nchunk = bid >> 2;
    btile = bid & 3;
  }
}

// ---------------- pass 0 (R18-validated): 2n per buffer, 512 thr ------------
__global__ __launch_bounds__(512, 1) void caps_pass0_mfma(
    const float* __restrict__ x, const char* __restrict__ wf16,
    __half* __restrict__ parts, int NC)
{
  __shared__ __align__(16) char arena[ARENA_P0];
  const int t = threadIdx.x;
  const int w = t >> 6, l = t & 63;
  int nchunk, btile;
  decode_bid(blockIdx.x, NC, nchunk, btile);
  const int n0 = (N_IN * nchunk) / NC;
  const int n1 = (N_IN * (nchunk + 1)) / NC;
  const int b0 = btile * 32;

  f32x16 acc[4];
#pragma unroll
  for (int q = 0; q < 4; ++q) acc[q] = (f32x16)(0.0f);

  stage_pair(arena, arena + P0X_OFF, wf16, x, n0, (n1 - n0 >= 2) ? 2 : 1, b0, t);

  int cur = 0;
  for (int base = n0; base < n1; base += 2) {
    const int cnt = (n1 - base >= 2) ? 2 : 1;
    __syncthreads();
    const char* wf = arena + cur * 65536;
    const char* xb = arena + P0X_OFF + cur * 4096;

    for (int s = 0; s < cnt; ++s) {
      const float4 xw0 = *(const float4*)(xb + s * 2048 + l * 16);
      const float4 xw1 = *(const float4*)(xb + s * 2048 + 1024 + l * 16);
      F16U bf;
      bf.u = uint4{pkh(xw0.x, xw0.y), pkh(xw0.z, xw0.w),
                   pkh(xw1.x, xw1.y), pkh(xw1.z, xw1.w)};
#pragma unroll
      for (int q = 0; q < 4; ++q) {
        const int j = w * 4 + q;
        const f16x8 af = *(const f16x8*)(wf + s * 32768 + j * 1024 + l * 16);
        acc[q] = __builtin_amdgcn_mfma_f32_32x32x16_f16(af, bf.f, acc[q], 0, 0, 0);
      }
    }

    if (base + 2 < n1) {
      const int ncnt = (n1 - (base + 2) >= 2) ? 2 : 1;
      stage_pair(arena + (cur ^ 1) * 65536, arena + P0X_OFF + (cur ^ 1) * 4096,
                 wf16, x, base + 2, ncnt, b0, t);
    }
    cur ^= 1;
  }
  store_parts(arena, parts, acc, 0.03125f, nchunk, b0, t);
}

// ------------- phases 1/2 (R20-validated): 1024 thr, 2 j/wave ---------------
__global__ __launch_bounds__(1024, 1) void caps_phase_mfma(
    const float* __restrict__ x, const char* __restrict__ wf16,
    const float* __restrict__ v,      // v0 (phase1) or v0+v1 (phase2)
    __half* __restrict__ parts, int NC)
{
  __shared__ __align__(16) char arena[ARENA_PH];
  const int t = threadIdx.x;
  const int w = t >> 6, l = t & 63;     // w 0..15
  const int b32 = l & 31, half = l >> 5;
  int nchunk, btile;
  decode_bid(blockIdx.x, NC, nchunk, btile);
  const int n0 = (N_IN * nchunk) / NC;
  const int n1 = (N_IN * (nchunk + 1)) / NC;
  const int b0 = btile * 32;

  // v gather ONCE into 16 packed-f16 regs (2 j's per wave):
  // vw[q][p] covers k=2p,2p+1; d(k) = (k&3)+8*(k>>2)+4*half (ut C-reg order).
  unsigned vw[2][8];
  {
    const int bv = b0 + b32;
#pragma unroll
    for (int q = 0; q < 2; ++q) {
      const int j = w * 2 + q;
#pragma unroll
      for (int g = 0; g < 4; ++g) {
        const float4 g4 = *(const float4*)(v + (size_t)bv * 1024 + j * 32 + g * 8 + 4 * half);
        vw[q][2 * g]     = pkh(g4.x, g4.y);
        vw[q][2 * g + 1] = pkh(g4.z, g4.w);
      }
    }
  }

  // prologue: stage tile n0 into buffer 0 (1024 thr: 2 x 16B each)
  {
    const char* src = wf16 + (size_t)n0 * 32768;
    *(uint4*)(arena + t * 16) = *(const uint4*)(src + t * 16);
    *(uint4*)(arena + 16384 + t * 16) = *(const uint4*)(src + 16384 + t * 16);
    if (t < 64) {
      const float4* xp = (const float4*)(x + ((size_t)(b0 + (t & 31)) * N_IN + n0) * 16 + (t >> 5) * 8);
      *(float4*)(arena + XF_OFF + t * 16) = xp[0];
      *(float4*)(arena + XF_OFF + 1024 + t * 16) = xp[1];
    }
  }

  f32x16 acc[2];
  acc[0] = (f32x16)(0.0f);
  acc[1] = (f32x16)(0.0f);

  int cur = 0;
  for (int n = n0; n < n1; ++n) {
    __syncthreads();                    // A: buf[cur] staged; lg free
    const char* wf = arena + cur * 32768;
    const char* xb = arena + XF_OFF + cur * 2048;
    char* nwf = arena + (cur ^ 1) * 32768;
    char* nxb = arena + XF_OFF + (cur ^ 1) * 2048;
    const bool more = (n + 1 < n1);

    const float4 xw0 = *(const float4*)(xb + l * 16);
    const float4 xw1 = *(const float4*)(xb + 1024 + l * 16);
    F16U bf;
    bf.u = uint4{pkh(xw0.x, xw0.y), pkh(xw0.z, xw0.w),
                 pkh(xw1.x, xw1.y), pkh(xw1.z, xw1.w)};

    // ---- logit pass: 2 j's per wave, transient u, dot v-regs, write lg ----
#pragma unroll
    for (int q = 0; q < 2; ++q) {
      const int j = w * 2 + q;
      const f16x8 af = *(const f16x8*)(wf + j * 1024 + l * 16);
      f32x16 ut = (f32x16)(0.0f);
      ut = __builtin_amdgcn_mfma_f32_32x32x16_f16(af, bf.f, ut, 0, 0, 0);
      float a = 0.f;
#pragma unroll
      for (int k = 0; k < 16; ++k) {
        const unsigned short us = (k & 1) ? (unsigned short)(vw[q][k >> 1] >> 16)
                                          : (unsigned short)(vw[q][k >> 1] & 0xFFFF);
        a = fmaf(ut[k], h2f(us), a);
      }
      a += __shfl_xor(a, 32);           // combine d-halves
      if (l < 32)                        // banks (b^j)&31 distinct: conflict-free
        *(float*)(arena + LG + (j * 32 + ((b32 ^ j) & 31)) * 4) = a;
    }
    __syncthreads();                    // B: logits complete

    // ---- softmax over j per b: ONE round (1024 = 32j x 32b slots) ----
    {
      const int jj = t & 31, b = t >> 5;
      float* slot = (float*)(arena + LG + (jj * 32 + ((b ^ jj) & 31)) * 4);
      float lgv = *slot;
      float mx = lgv;
#pragma unroll
      for (int off = 16; off >= 1; off >>= 1) mx = fmaxf(mx, __shfl_xor(mx, off));
      const float e = __expf(lgv - mx);
      float Z = e;
#pragma unroll
      for (int off = 16; off >= 1; off >>= 1) Z += __shfl_xor(Z, off);
      *slot = e / Z;
    }

    // stage next tile inline (drains at next A; issued here so C+s-pass cover)
    if (more) {
      const char* src = wf16 + (size_t)(n + 1) * 32768;
      *(uint4*)(nwf + t * 16) = *(const uint4*)(src + t * 16);
      *(uint4*)(nwf + 16384 + t * 16) = *(const uint4*)(src + 16384 + t * 16);
      if (t < 64) {
        const float4* xp = (const float4*)(x + ((size_t)(b0 + (t & 31)) * N_IN + n + 1) * 16 + (t >> 5) * 8);
        *(float4*)(nxb + t * 16) = xp[0];
        *(float4*)(nxb + 1024 + t * 16) = xp[1];
      }
    }
    __syncthreads();                    // C: c visible

    // ---- s pass: B = f16(c_j * x), accumulate into persistent acc ----
#pragma unroll
    for (int q = 0; q < 2; ++q) {
      const int j = w * 2 + q;
      const float cj = *(const float*)(arena + LG + (j * 32 + ((b32 ^ j) & 31)) * 4);
      F16U yf;
      yf.u = uint4{pkh(cj * xw0.x, cj * xw0.y), pkh(cj * xw0.z, cj * xw0.w),
                   pkh(cj * xw1.x, cj * xw1.y), pkh(cj * xw1.z, cj * xw1.w)};
      const f16x8 af = *(const f16x8*)(wf + j * 1024 + l * 16);
      acc[q] = __builtin_amdgcn_mfma_f32_32x32x16_f16(af, yf.f, acc[q], 0, 0, 0);
    }
    cur ^= 1;
  }

  // epilogue (1024-thr, 2 rounds over b-halves, [16][1036] f32 reuse)
#pragma unroll
  for (int r = 0; r < 2; ++r) {
    __syncthreads();
    if ((b32 >> 4) == r) {
      const int b16 = b32 & 15;
#pragma unroll
      for (int q = 0; q < 2; ++q) {
        const int j = w * 2 + q;
#pragma unroll
        for (int g = 0; g < 4; ++g) {
          float4 v4;
          v4.x = acc[q][g * 4 + 0];
          v4.y = acc[q][g * 4 + 1];
          v4.z = acc[q][g * 4 + 2];
          v4.w = acc[q][g * 4 + 3];
          *(float4*)(arena + (b16 * 1036 + j * 32 + g * 8 + 4 * half) * 4) = v4;
        }
      }
    }
    __syncthreads();
    char* pb = (char*)(parts + (size_t)nchunk * ELEMS + (size_t)(b0 + r * 16) * 1024);
    const int rb = t >> 6, c64 = t & 63;   // 16 rows x 64 threads
#pragma unroll
    for (int q2 = 0; q2 < 2; ++q2) {
      const int g8 = c64 + q2 * 64;        // 8-f32 group 0..127
      const float4 a = *(const float4*)(arena + (rb * 1036 + g8 * 8) * 4);
      const float4 b = *(const float4*)(arena + (rb * 1036 + g8 * 8 + 4) * 4);
      *(uint4*)(pb + rb * 2048 + g8 * 16) =
          uint4{pkh(a.x, a.y), pkh(a.z, a.w), pkh(b.x, b.y), pkh(b.z, b.w)};
    }
  }
}

// stage B: sum NC f16 partials (4 elems/thread via uint2), squash over rows
// of 32 (= 8 threads: in-thread 4 + shfl over offs 4,2,1); add prev v if set.
__global__ void reduce_squash4(const unsigned short* __restrict__ parts, int NC,
                               float* __restrict__ out,
                               const float* __restrict__ addprev) {
  const int e0 = (blockIdx.x * 256 + threadIdx.x) * 4;
  float s0 = 0.f, s1 = 0.f, s2v = 0.f, s3 = 0.f;
  for (int c = 0; c < NC; ++c) {
    const uint2 p = *(const uint2*)(parts + (size_t)c * ELEMS + e0);
    s0 += h2f((unsigned short)(p.x & 0xFFFF));
    s1 += h2f((unsigned short)(p.x >> 16));
    s2v += h2f((unsigned short)(p.y & 0xFFFF));
    s3 += h2f((unsigned short)(p.y >> 16));
  }
  float s2 = s0 * s0 + s1 * s1 + s2v * s2v + s3 * s3;
#pragma unroll
  for (int off = 4; off >= 1; off >>= 1) s2 += __shfl_xor(s2, off);
  const float scale = (s2 / (1.0f + s2)) * rsqrtf(s2 + 1e-7f);
  float4 o;
  o.x = s0 * scale; o.y = s1 * scale; o.z = s2v * scale; o.w = s3 * scale;
  if (addprev) {
    const float4 ap = *(const float4*)(addprev + e0);
    o.x += ap.x; o.y += ap.y; o.z += ap.z; o.w += ap.w;
  }
  *(float4*)(out + e0) = o;
}

extern "C" void kernel_launch(void* const* d_in, const int* in_sizes, int n_in,
                              void* d_out, int out_size, void* d_ws, size_t ws_size,
                              hipStream_t stream) {
  const float* x = (const float*)d_in[0];
  const float* W = (const float*)d_in[1];
  float* out = (float*)d_out;

  float* v0 = (float*)d_ws;
  float* vsum = v0 + ELEMS;
  char* wf16 = (char*)d_ws + WF16_OFF;
  __half* parts = (__half*)((char*)d_ws + PARTS_OFF);

  // NC from remaining workspace (deterministic); NC=64 -> grid 256 = 1/CU
  size_t rem = ws_size > (size_t)PARTS_OFF ? ws_size - PARTS_OFF : 0;
  int NC = (int)(rem / (ELEMS * 2));
  NC = NC < 1 ? 1 : (NC > 64 ? 64 : NC);

  const dim3 blk512(512);
  const dim3 blk1k(1024);
  const dim3 gridP(NC * 4);
  const dim3 gridR(128);
  const dim3 blkR(256);

  cvt_w_f16<<<dim3(N_IN), blk512, 0, stream>>>(W, wf16);

  caps_pass0_mfma<<<gridP, blk512, 0, stream>>>(x, wf16, parts, NC);
  reduce_squash4<<<gridR, blkR, 0, stream>>>((const unsigned short*)parts, NC, v0, nullptr);

  caps_phase_mfma<<<gridP, blk1k, 0, stream>>>(x, wf16, v0, parts, NC);
  reduce_squash4<<<gridR, blkR, 0, stream>>>((const unsigned short*)parts, NC, vsum, v0);

  caps_phase_mfma<<<gridP, blk1k, 0, stream>>>(x, wf16, vsum, parts, NC);
  reduce_squash4<<<gridR, blkR, 0, stream>>>((const unsigned short*)parts, NC, out, nullptr);
}

// Round 24
// 141.235 us; speedup vs baseline: 1.1333x; 1.0385x over previous
//
#include <hip/hip_runtime.h>
#include <hip/hip_fp16.h>
#include <math.h>

// StressCapsuleLayer: capsule dynamic routing (3 iters), fused recompute design.
//   x [128][648][16] f32, W [648][32][32][16] f32 -> v [128][32][32] f32
//
//   pass0: c = 1/32 -> s0 -> v0 = squash(s0)            [f16 MFMA GEMM]
//   pass1: logit = <u_hat, v0>          -> softmax_j -> s1 -> v1
//   pass2: logit = <u, v0+v1> (linear)  -> softmax_j -> s2 -> v2 = output
//
// R24: restore R20 exactly (141.5us, session best). R21/R23's vectorized
// reduce4 (128x256 = 512 waves = 2/CU) was latency-bound (Guideline 11:
// gather reductions need TLP) -- scalar reduce at 512x256 blocks = 2048
// waves is faster despite more instructions. Phase (1024-thr, 2 j/wave,
// nothing live across barriers) + pass0 (512-thr, 2n/buffer) + cvt are
// R20-identical. This is the measured optimum of the explored space:
// per-n cost invariants (R13-R19), TLP win (R20), VGPR caps (R16/R22),
// all documented in-session.

#define N_IN 648
#define ELEMS 131072      // 128*32*32 output elements

// d_ws layout (bytes): v0 @0 (512KB), vsum @524288, wf16 @1048576 (21233664),
// parts(f16) @22282240 (NC x 262144)
#define WF16_OFF 1048576
#define PARTS_OFF 22282240

// pass0 LDS arena (R18): WF[2] @0/65536 (2n x 32KB), X[2] @131072/135168.
// Epilogue reuse [32][1036] f32 = 132608 <= 147456.
#define P0X_OFF 131072
#define ARENA_P0 147456

// phase LDS arena: WF[2] @0/32768, X[2] @65536/67584 (2KB each), LG @69632
// (4KB). Epilogue reuse [16][1036] f32 = 66304 <= 73728.
#define XF_OFF 65536
#define LG 69632
#define ARENA_PH 73728

typedef __attribute__((ext_vector_type(8))) _Float16 f16x8;
typedef __attribute__((ext_vector_type(16))) float f32x16;

union F16U { uint4 u; f16x8 f; };
union HU { __half h; unsigned short us; };

__device__ __forceinline__ unsigned pkh(float a, float b) {
  HU x, y; x.h = __float2half(a); y.h = __float2half(b);
  return (unsigned)x.us | ((unsigned)y.us << 16);
}
__device__ __forceinline__ float h2f(unsigned short u) {
  HU x; x.us = u; return __half2float(x.h);
}

// cvt one W row (16 f32 in r[0..3]) to f16, write its two frag slots:
// (d,h=0) = i0..7 at jS*1024 + d*16; (d,h=1) = i8..15 at +512.
__device__ __forceinline__ void writeW(char* wbuf, int jS, int d, const float4* r) {
  uint4 h0, h1;
  h0.x = pkh(r[0].x, r[0].y); h0.y = pkh(r[0].z, r[0].w);
  h0.z = pkh(r[1].x, r[1].y); h0.w = pkh(r[1].z, r[1].w);
  h1.x = pkh(r[2].x, r[2].y); h1.y = pkh(r[2].z, r[2].w);
  h1.z = pkh(r[3].x, r[3].y); h1.w = pkh(r[3].z, r[3].w);
  *(uint4*)(wbuf + jS * 1024 + d * 16) = h0;
  *(uint4*)(wbuf + jS * 1024 + 512 + d * 16) = h1;
}
__device__ __forceinline__ void loadW(float4* r, const float* __restrict__ W,
                                      int n, int jS, int d) {
  const float4* rp = (const float4*)(W + (size_t)n * 16384 + jS * 512 + d * 16);
  r[0] = rp[0]; r[1] = rp[1]; r[2] = rp[2]; r[3] = rp[3];
}

// one-time: W f32 -> f16 frag-layout blocks in d_ws (32KB per n)
__global__ __launch_bounds__(512) void cvt_w_f16(const float* __restrict__ W,
                                                 char* __restrict__ wf) {
  const int n = blockIdx.x;
  const int t = threadIdx.x;
  const int jS = t >> 4, m = t & 15;
  float4 rA[4], rB[4];
  loadW(rA, W, n, jS, m);
  loadW(rB, W, n, jS, m + 16);
  char* dst = wf + (size_t)n * 32768;
  writeW(dst, jS, m, rA);
  writeW(dst, jS, m + 16, rB);
}

// stage cnt (1 or 2) consecutive n's of Wf16 + x rows (512-thread version)
__device__ __forceinline__ void stage_pair(char* nwf, char* nxb,
                                           const char* __restrict__ wf16,
                                           const float* __restrict__ x,
                                           int nbase, int cnt, int b0, int t) {
  const char* src = wf16 + (size_t)nbase * 32768;
  for (int r = 0; r < cnt * 4; ++r)
    *(uint4*)(nwf + r * 8192 + t * 16) = *(const uint4*)(src + r * 8192 + t * 16);
  if (t < 128) {
    const int s2 = t >> 6, u = t & 63;
    if (s2 < cnt) {
      const float4* xp = (const float4*)(
          x + ((size_t)(b0 + (u & 31)) * N_IN + nbase + s2) * 16 + (u >> 5) * 8);
      *(float4*)(nxb + s2 * 2048 + u * 16) = xp[0];
      *(float4*)(nxb + s2 * 2048 + 1024 + u * 16) = xp[1];
    }
  }
}

// 512-thr epilogue (pass0): scatter acc ([32][1036] reuse), f16 parts.
__device__ __forceinline__ void store_parts(char* arena, __half* __restrict__ parts,
                                            const f32x16* acc, float scale,
                                            int nchunk, int b0, int t) {
  const int w = t >> 6, l = t & 63;
  const int b32 = l & 31, half = l >> 5;
  __syncthreads();
#pragma unroll
  for (int q = 0; q < 4; ++q) {
    const int j = w * 4 + q;
#pragma unroll
    for (int g = 0; g < 4; ++g) {
      float4 v4;
      v4.x = acc[q][g * 4 + 0] * scale;
      v4.y = acc[q][g * 4 + 1] * scale;
      v4.z = acc[q][g * 4 + 2] * scale;
      v4.w = acc[q][g * 4 + 3] * scale;
      *(float4*)(arena + (b32 * 1036 + j * 32 + g * 8 + 4 * half) * 4) = v4;
    }
  }
  __syncthreads();
  char* pb = (char*)(parts + (size_t)nchunk * ELEMS + (size_t)b0 * 1024);
  const int rb = t >> 4, c16 = t & 15;
#pragma unroll
  for (int q = 0; q < 8; ++q) {
    const int g8 = c16 + q * 16;
    const float4 a = *(const float4*)(arena + (rb * 1036 + g8 * 8) * 4);
    const float4 b = *(const float4*)(arena + (rb * 1036 + g8 * 8 + 4) * 4);
    *(uint4*)(pb + rb * 2048 + g8 * 16) =
        uint4{pkh(a.x, a.y), pkh(a.z, a.w), pkh(b.x, b.y), pkh(b.z, b.w)};
  }
}

// XCD-aware decode: 4 btile-sharers of an n-chunk -> same XCD
__device__ __forceinline__ void decode_bid(int bid, int NC, int& nchunk, int& btile) {
  if ((NC & 7) == 0) {
    const int r = bid & 7;
    btile = (bid >> 3) & 3;
    nchunk = (bid >> 5) * 8 + r;
  } else {
    nchunk = bid >> 2;
    btile = bid & 3;
  }
}

// ---------------- pass 0 (R18-validated): 2n per buffer, 512 thr ------------
__global__ __launch_bounds__(512, 1) void caps_pass0_mfma(
    const float* __restrict__ x, const char* __restrict__ wf16,
    __half* __restrict__ parts, int NC)
{
  __shared__ __align__(16) char arena[ARENA_P0];
  const int t = threadIdx.x;
  const int w = t >> 6, l = t & 63;
  int nchunk, btile;
  decode_bid(blockIdx.x, NC, nchunk, btile);
  const int n0 = (N_IN * nchunk) / NC;
  const int n1 = (N_IN * (nchunk + 1)) / NC;
  const int b0 = btile * 32;

  f32x16 acc[4];
#pragma unroll
  for (int q = 0; q < 4; ++q) acc[q] = (f32x16)(0.0f);

  stage_pair(arena, arena + P0X_OFF, wf16, x, n0, (n1 - n0 >= 2) ? 2 : 1, b0, t);

  int cur = 0;
  for (int base = n0; base < n1; base += 2) {
    const int cnt = (n1 - base >= 2) ? 2 : 1;
    __syncthreads();
    const char* wf = arena + cur * 65536;
    const char* xb = arena + P0X_OFF + cur * 4096;

    for (int s = 0; s < cnt; ++s) {
      const float4 xw0 = *(const float4*)(xb + s * 2048 + l * 16);
      const float4 xw1 = *(const float4*)(xb + s * 2048 + 1024 + l * 16);
      F16U bf;
      bf.u = uint4{pkh(xw0.x, xw0.y), pkh(xw0.z, xw0.w),
                   pkh(xw1.x, xw1.y), pkh(xw1.z, xw1.w)};
#pragma unroll
      for (int q = 0; q < 4; ++q) {
        const int j = w * 4 + q;
        const f16x8 af = *(const f16x8*)(wf + s * 32768 + j * 1024 + l * 16);
        acc[q] = __builtin_amdgcn_mfma_f32_32x32x16_f16(af, bf.f, acc[q], 0, 0, 0);
      }
    }

    if (base + 2 < n1) {
      const int ncnt = (n1 - (base + 2) >= 2) ? 2 : 1;
      stage_pair(arena + (cur ^ 1) * 65536, arena + P0X_OFF + (cur ^ 1) * 4096,
                 wf16, x, base + 2, ncnt, b0, t);
    }
    cur ^= 1;
  }
  store_parts(arena, parts, acc, 0.03125f, nchunk, b0, t);
}

// ------------- phases 1/2 (R20-validated): 1024 thr, 2 j/wave ---------------
__global__ __launch_bounds__(1024, 1) void caps_phase_mfma(
    const float* __restrict__ x, const char* __restrict__ wf16,
    const float* __restrict__ v,      // v0 (phase1) or v0+v1 (phase2)
    __half* __restrict__ parts, int NC)
{
  __shared__ __align__(16) char arena[ARENA_PH];
  const int t = threadIdx.x;
  const int w = t >> 6, l = t & 63;     // w 0..15
  const int b32 = l & 31, half = l >> 5;
  int nchunk, btile;
  decode_bid(blockIdx.x, NC, nchunk, btile);
  const int n0 = (N_IN * nchunk) / NC;
  const int n1 = (N_IN * (nchunk + 1)) / NC;
  const int b0 = btile * 32;

  // v gather ONCE into 16 packed-f16 regs (2 j's per wave):
  // vw[q][p] covers k=2p,2p+1; d(k) = (k&3)+8*(k>>2)+4*half (ut C-reg order).
  unsigned vw[2][8];
  {
    const int bv = b0 + b32;
#pragma unroll
    for (int q = 0; q < 2; ++q) {
      const int j = w * 2 + q;
#pragma unroll
      for (int g = 0; g < 4; ++g) {
        const float4 g4 = *(const float4*)(v + (size_t)bv * 1024 + j * 32 + g * 8 + 4 * half);
        vw[q][2 * g]     = pkh(g4.x, g4.y);
        vw[q][2 * g + 1] = pkh(g4.z, g4.w);
      }
    }
  }

  // prologue: stage tile n0 into buffer 0 (1024 thr: 2 x 16B each)
  {
    const char* src = wf16 + (size_t)n0 * 32768;
    *(uint4*)(arena + t * 16) = *(const uint4*)(src + t * 16);
    *(uint4*)(arena + 16384 + t * 16) = *(const uint4*)(src + 16384 + t * 16);
    if (t < 64) {
      const float4* xp = (const float4*)(x + ((size_t)(b0 + (t & 31)) * N_IN + n0) * 16 + (t >> 5) * 8);
      *(float4*)(arena + XF_OFF + t * 16) = xp[0];
      *(float4*)(arena + XF_OFF + 1024 + t * 16) = xp[1];
    }
  }

  f32x16 acc[2];
  acc[0] = (f32x16)(0.0f);
  acc[1] = (f32x16)(0.0f);

  int cur = 0;
  for (int n = n0; n < n1; ++n) {
    __syncthreads();                    // A: buf[cur] staged; lg free
    const char* wf = arena + cur * 32768;
    const char* xb = arena + XF_OFF + cur * 2048;
    char* nwf = arena + (cur ^ 1) * 32768;
    char* nxb = arena + XF_OFF + (cur ^ 1) * 2048;
    const bool more = (n + 1 < n1);

    const float4 xw0 = *(const float4*)(xb + l * 16);
    const float4 xw1 = *(const float4*)(xb + 1024 + l * 16);
    F16U bf;
    bf.u = uint4{pkh(xw0.x, xw0.y), pkh(xw0.z, xw0.w),
                 pkh(xw1.x, xw1.y), pkh(xw1.z, xw1.w)};

    // ---- logit pass: 2 j's per wave, transient u, dot v-regs, write lg ----
#pragma unroll
    for (int q = 0; q < 2; ++q) {
      const int j = w * 2 + q;
      const f16x8 af = *(const f16x8*)(wf + j * 1024 + l * 16);
      f32x16 ut = (f32x16)(0.0f);
      ut = __builtin_amdgcn_mfma_f32_32x32x16_f16(af, bf.f, ut, 0, 0, 0);
      float a = 0.f;
#pragma unroll
      for (int k = 0; k < 16; ++k) {
        const unsigned short us = (k & 1) ? (unsigned short)(vw[q][k >> 1] >> 16)
                                          : (unsigned short)(vw[q][k >> 1] & 0xFFFF);
        a = fmaf(ut[k], h2f(us), a);
      }
      a += __shfl_xor(a, 32);           // combine d-halves
      if (l < 32)                        // banks (b^j)&31 distinct: conflict-free
        *(float*)(arena + LG + (j * 32 + ((b32 ^ j) & 31)) * 4) = a;
    }
    __syncthreads();                    // B: logits complete

    // ---- softmax over j per b: ONE round (1024 = 32j x 32b slots) ----
    {
      const int jj = t & 31, b = t >> 5;
      float* slot = (float*)(arena + LG + (jj * 32 + ((b ^ jj) & 31)) * 4);
      float lgv = *slot;
      float mx = lgv;
#pragma unroll
      for (int off = 16; off >= 1; off >>= 1) mx = fmaxf(mx, __shfl_xor(mx, off));
      const float e = __expf(lgv - mx);
      float Z = e;
#pragma unroll
      for (int off = 16; off >= 1; off >>= 1) Z += __shfl_xor(Z, off);
      *slot = e / Z;
    }

    // stage next tile inline (drains at next A; issued here so C+s-pass cover)
    if (more) {
      const char* src = wf16 + (size_t)(n + 1) * 32768;
      *(uint4*)(nwf + t * 16) = *(const uint4*)(src + t * 16);
      *(uint4*)(nwf + 16384 + t * 16) = *(const uint4*)(src + 16384 + t * 16);
      if (t < 64) {
        const float4* xp = (const float4*)(x + ((size_t)(b0 + (t & 31)) * N_IN + n + 1) * 16 + (t >> 5) * 8);
        *(float4*)(nxb + t * 16) = xp[0];
        *(float4*)(nxb + 1024 + t * 16) = xp[1];
      }
    }
    __syncthreads();                    // C: c visible

    // ---- s pass: B = f16(c_j * x), accumulate into persistent acc ----
#pragma unroll
    for (int q = 0; q < 2; ++q) {
      const int j = w * 2 + q;
      const float cj = *(const float*)(arena + LG + (j * 32 + ((b32 ^ j) & 31)) * 4);
      F16U yf;
      yf.u = uint4{pkh(cj * xw0.x, cj * xw0.y), pkh(cj * xw0.z, cj * xw0.w),
                   pkh(cj * xw1.x, cj * xw1.y), pkh(cj * xw1.z, cj * xw1.w)};
      const f16x8 af = *(const f16x8*)(wf + j * 1024 + l * 16);
      acc[q] = __builtin_amdgcn_mfma_f32_32x32x16_f16(af, yf.f, acc[q], 0, 0, 0);
    }
    cur ^= 1;
  }

  // epilogue (1024-thr, 2 rounds over b-halves, [16][1036] f32 reuse)
#pragma unroll
  for (int r = 0; r < 2; ++r) {
    __syncthreads();
    if ((b32 >> 4) == r) {
      const int b16 = b32 & 15;
#pragma unroll
      for (int q = 0; q < 2; ++q) {
        const int j = w * 2 + q;
#pragma unroll
        for (int g = 0; g < 4; ++g) {
          float4 v4;
          v4.x = acc[q][g * 4 + 0];
          v4.y = acc[q][g * 4 + 1];
          v4.z = acc[q][g * 4 + 2];
          v4.w = acc[q][g * 4 + 3];
          *(float4*)(arena + (b16 * 1036 + j * 32 + g * 8 + 4 * half) * 4) = v4;
        }
      }
    }
    __syncthreads();
    char* pb = (char*)(parts + (size_t)nchunk * ELEMS + (size_t)(b0 + r * 16) * 1024);
    const int rb = t >> 6, c64 = t & 63;   // 16 rows x 64 threads
#pragma unroll
    for (int q2 = 0; q2 < 2; ++q2) {
      const int g8 = c64 + q2 * 64;        // 8-f32 group 0..127
      const float4 a = *(const float4*)(arena + (rb * 1036 + g8 * 8) * 4);
      const float4 b = *(const float4*)(arena + (rb * 1036 + g8 * 8 + 4) * 4);
      *(uint4*)(pb + rb * 2048 + g8 * 16) =
          uint4{pkh(a.x, a.y), pkh(a.z, a.w), pkh(b.x, b.y), pkh(b.z, b.w)};
    }
  }
}

// stage B (R20-validated scalar form, 2048 waves): sum NC f16 partials,
// squash over last dim (32) via width-32 shuffle; add prev v if set.
__global__ void reduce_squash(const unsigned short* __restrict__ parts, int NC,
                              float* __restrict__ out,
                              const float* __restrict__ addprev) {
  const int e = blockIdx.x * 256 + threadIdx.x;
  float s = 0.f;
  for (int c = 0; c < NC; ++c) s += h2f(parts[(size_t)c * ELEMS + e]);
  float s2 = s * s;
#pragma unroll
  for (int off = 16; off >= 1; off >>= 1) s2 += __shfl_xor(s2, off);
  const float scale = (s2 / (1.0f + s2)) * rsqrtf(s2 + 1e-7f);
  const float val = s * scale;
  out[e] = addprev ? (addprev[e] + val) : val;
}

extern "C" void kernel_launch(void* const* d_in, const int* in_sizes, int n_in,
                              void* d_out, int out_size, void* d_ws, size_t ws_size,
                              hipStream_t stream) {
  const float* x = (const float*)d_in[0];
  const float* W = (const float*)d_in[1];
  float* out = (float*)d_out;

  float* v0 = (float*)d_ws;
  float* vsum = v0 + ELEMS;
  char* wf16 = (char*)d_ws + WF16_OFF;
  __half* parts = (__half*)((char*)d_ws + PARTS_OFF);

  // NC from remaining workspace (deterministic); NC=64 -> grid 256 = 1/CU
  size_t rem = ws_size > (size_t)PARTS_OFF ? ws_size - PARTS_OFF : 0;
  int NC = (int)(rem / (ELEMS * 2));
  NC = NC < 1 ? 1 : (NC > 64 ? 64 : NC);

  const dim3 blk512(512);
  const dim3 blk1k(1024);
  const dim3 gridP(NC * 4);

  cvt_w_f16<<<dim3(N_IN), blk512, 0, stream>>>(W, wf16);

  caps_pass0_mfma<<<gridP, blk512, 0, stream>>>(x, wf16, parts, NC);
  reduce_squash<<<512, 256, 0, stream>>>((const unsigned short*)parts, NC, v0, nullptr);

  caps_phase_mfma<<<gridP, blk1k, 0, stream>>>(x, wf16, v0, parts, NC);
  reduce_squash<<<512, 256, 0, stream>>>((const unsigned short*)parts, NC, vsum, v0);

  caps_phase_mfma<<<gridP, blk1k, 0, stream>>>(x, wf16, vsum, parts, NC);
  reduce_squash<<<512, 256, 0, stream>>>((const unsigned short*)parts, NC, out, nullptr);
}